// Round 6
// baseline (512.132 us; speedup 1.0000x reference)
//
#include <hip/hip_runtime.h>
#include <hip/hip_bf16.h>

#define NN 100000
#define EE 640000
#define DD 128
#define RR 8
#define K8 (NN * RR)      // 800000 (src,rel) pair keys
#define NSB1 25           // ceil(NN/4096)
#define NSB2 196          // ceil(K8/4096)

typedef __attribute__((ext_vector_type(8))) short short8;
typedef __attribute__((ext_vector_type(4))) float floatx4;
typedef __attribute__((ext_vector_type(4))) unsigned int uint4v;

__device__ __forceinline__ unsigned short f2bf(float f) {
  unsigned int u = __float_as_uint(f);
  u += 0x7FFFu + ((u >> 16) & 1u);   // RNE
  return (unsigned short)(u >> 16);
}
__device__ __forceinline__ unsigned int pk2bf(float a, float b) {
  __hip_bfloat162 h = __float22bfloat162_rn(make_float2(a, b));
  unsigned int u;
  __builtin_memcpy(&u, &h, 4);
  return u;                          // low16 = a, high16 = b
}
__device__ __forceinline__ float bflo(unsigned int u) { return __uint_as_float(u << 16); }
__device__ __forceinline__ float bfhi(unsigned int u) { return __uint_as_float(u & 0xFFFF0000u); }

// ---------------------------------------------------------------------------
// Both layers' weights: wt[set][r][n][k] = bf16(W[k][n]); r=8 is root.
// ---------------------------------------------------------------------------
__global__ __launch_bounds__(256) void w_prep_all(
    const float* __restrict__ rel1, const float* __restrict__ root1,
    const float* __restrict__ rel2, const float* __restrict__ root2,
    unsigned short* __restrict__ wt)
{
  int id = blockIdx.x * 256 + threadIdx.x;       // [0, 2*9*16384)
  int set = id >= 147456;
  int rem = id - set * 147456;
  int r = rem >> 14, n = (rem >> 7) & 127, k = rem & 127;
  const float* rel = set ? rel2 : rel1;
  const float* root = set ? root2 : root1;
  float v = (r < RR) ? rel[((size_t)r * DD + k) * DD + n] : root[(size_t)k * DD + n];
  wt[id] = f2bf(v);
}

// ---------------------------------------------------------------------------
// Counts: per-dst degree, per-(dst,r) degree (scale), per-(src,r) usage.
// ---------------------------------------------------------------------------
__global__ __launch_bounds__(256) void count_all(
    const int* __restrict__ ei, const int* __restrict__ et,
    int* __restrict__ cntd, int* __restrict__ cntdr, int* __restrict__ cntsr)
{
  int e = blockIdx.x * 256 + threadIdx.x;
  int src = ei[e], dst = ei[EE + e], r = et[e];
  atomicAdd(&cntd[dst], 1);
  atomicAdd(&cntdr[dst * RR + r], 1);
  atomicAdd(&cntsr[src * RR + r], 1);
}

// ---------------------------------------------------------------------------
// Generic 3-phase exclusive scan. mode 0: sum values; mode 1: count nonzero.
// ---------------------------------------------------------------------------
__global__ __launch_bounds__(256) void scan_a(
    const int4* __restrict__ c4, int n4, int mode, int* __restrict__ bsum)
{
  int t = threadIdx.x;
  int s = 0;
#pragma unroll
  for (int i = 0; i < 4; ++i) {
    int idx = blockIdx.x * 1024 + i * 256 + t;
    if (idx < n4) {
      int4 v = c4[idx];
      if (mode) s += (v.x > 0) + (v.y > 0) + (v.z > 0) + (v.w > 0);
      else      s += v.x + v.y + v.z + v.w;
    }
  }
  __shared__ int wsum[4];
  for (int d = 32; d; d >>= 1) s += __shfl_xor(s, d, 64);
  if ((t & 63) == 0) wsum[t >> 6] = s;
  __syncthreads();
  if (t == 0) bsum[blockIdx.x] = wsum[0] + wsum[1] + wsum[2] + wsum[3];
}

__global__ void scan_b(const int* __restrict__ bsum, int nsb,
                       int* __restrict__ bbase, int* __restrict__ tot)
{
  int lane = threadIdx.x;                         // 64 threads
  int v[4]; int s = 0;
#pragma unroll
  for (int i = 0; i < 4; ++i) {
    int idx = lane * 4 + i;
    v[i] = (idx < nsb) ? bsum[idx] : 0; s += v[i];
  }
  int inc = s;
  for (int d = 1; d < 64; d <<= 1) {
    int o = __shfl_up(inc, d, 64);
    if (lane >= d) inc += o;
  }
  int running = inc - s;
#pragma unroll
  for (int i = 0; i < 4; ++i) {
    int idx = lane * 4 + i;
    if (idx < nsb) { bbase[idx] = running; running += v[i]; }
  }
  if (lane == 63 && tot != nullptr) tot[0] = inc;
}

// mode 0: out0=rowptr (and out0[n]=EE by block0), out1=rowfill.
// mode 1: out0=pidx (compact index or -1).
__global__ __launch_bounds__(256) void scan_c(
    const int* __restrict__ cnt, const int* __restrict__ bbase, int n, int mode,
    int* __restrict__ out0, int* __restrict__ out1)
{
  int t = threadIdx.x;
  int base = blockIdx.x * 4096 + t * 16;
  int v[16]; int s = 0;
#pragma unroll
  for (int i = 0; i < 16; ++i) {
    int idx = base + i;
    v[i] = (idx < n) ? cnt[idx] : 0;
    s += mode ? (v[i] > 0) : v[i];
  }
  int lane = t & 63, wid = t >> 6;
  int inc = s;
  for (int d = 1; d < 64; d <<= 1) {
    int o = __shfl_up(inc, d, 64);
    if (lane >= d) inc += o;
  }
  __shared__ int wsum[4];
  if (lane == 63) wsum[wid] = inc;
  __syncthreads();
  int wb = 0;
  for (int w = 0; w < wid; ++w) wb += wsum[w];
  int running = bbase[blockIdx.x] + wb + (inc - s);
#pragma unroll
  for (int i = 0; i < 16; ++i) {
    int idx = base + i;
    if (idx < n) {
      if (mode) { out0[idx] = (v[i] > 0) ? running : -1; running += (v[i] > 0); }
      else      { out0[idx] = running; out1[idx] = running; running += v[i]; }
    }
  }
  if (!mode && blockIdx.x == 0 && t == 0) out0[n] = EE;
}

// ---------------------------------------------------------------------------
// Place edges into dst-major CSR: rec = (compact yrow of (src,r), scale(dst,r))
// ---------------------------------------------------------------------------
__global__ __launch_bounds__(256) void place2(
    const int* __restrict__ ei, const int* __restrict__ et,
    const int* __restrict__ cntdr, const int* __restrict__ pidx,
    int* __restrict__ rowfill, int2* __restrict__ recs)
{
  int e = blockIdx.x * 256 + threadIdx.x;
  int src = ei[e], dst = ei[EE + e], r = et[e];
  int slot = atomicAdd(&rowfill[dst], 1);
  float s = 1.0f / (float)max(cntdr[dst * RR + r], 1);
  int2 rec; rec.x = pidx[src * RR + r]; rec.y = __float_as_int(s);
  recs[slot] = rec;
}

// ---------------------------------------------------------------------------
// GEMM: for each node v (64-row tiles), 9 rounds r: Y[yrow(v,r)] = bf16(Xv @ W_r),
// stored only if yrow>=0 (pair used; root r=8 always at Ptot+v).
// A-fragments register-resident; W double-buffered; yidx in dead As LDS.
// Ypk row layout: uint u = nip*16+mr -> cols 32*nip+mr and 32*nip+16+mr.
// ---------------------------------------------------------------------------
__global__ __launch_bounds__(256, 2) void gemm_y(
    const void* __restrict__ Xin, int in_f32,
    const unsigned short* __restrict__ Wt,   // [9][128][128] bf16 [r][n][k]
    const int* __restrict__ pidx,            // [K8]
    const int* __restrict__ Ptot,            // [1]
    unsigned int* __restrict__ Ypk)
{
  __shared__ unsigned short As[64 * 128];    // 16 KB (dead after frag load -> yidx alias)
  __shared__ unsigned short Ws[2][128 * 128];// 64 KB
  int* yidxL = (int*)As;                     // 576 ints, aliased after frag load
  const int tid = threadIdx.x;
  const int row0 = blockIdx.x * 64;
  const int wave = tid >> 6, lane = tid & 63;
  const int quad = lane >> 4, mr = lane & 15;

  // ---- stage A (rotated by (row&15)*8 shorts) ----
  {
    int row = tid >> 2, q = tid & 3, grow = row0 + row;
    if (in_f32) {
      const float4* xs = (const float4*)((const float*)Xin + (size_t)grow * 128 + q * 32);
#pragma unroll
      for (int c = 0; c < 4; ++c) {
        uint4v v = {0u, 0u, 0u, 0u};
        if (grow < NN) {
          float4 va = xs[c * 2], vb = xs[c * 2 + 1];
          v[0] = pk2bf(va.x, va.y); v[1] = pk2bf(va.z, va.w);
          v[2] = pk2bf(vb.x, vb.y); v[3] = pk2bf(vb.z, vb.w);
        }
        int pos = (q * 32 + c * 8 + (row & 15) * 8) & 127;
        *(uint4v*)&As[row * 128 + pos] = v;
      }
    } else {
      const uint4v* xs = (const uint4v*)((const unsigned int*)Xin + (size_t)grow * 64 + q * 16);
#pragma unroll
      for (int c = 0; c < 4; ++c) {
        uint4v v = (grow < NN) ? xs[c] : (uint4v){0u, 0u, 0u, 0u};
        int pos = (q * 32 + c * 8 + (row & 15) * 8) & 127;
        *(uint4v*)&As[row * 128 + pos] = v;
      }
    }
  }
  // ---- stage Ws[0] ----
  {
    int n = tid >> 1, half = tid & 1;
    const uint4v* wsrc = (const uint4v*)(Wt + (size_t)n * 128) + half * 8;
#pragma unroll
    for (int k = 0; k < 8; ++k) {
      uint4v v = wsrc[k];
      int pos = (half * 64 + k * 8 + (n & 15) * 8) & 127;
      *(uint4v*)&Ws[0][n * 128 + pos] = v;
    }
  }
  __syncthreads();

  // ---- A fragments: register-resident for all rounds ----
  short8 a[4];
  {
    int arow = wave * 16 + mr;
#pragma unroll
    for (int ks = 0; ks < 4; ++ks)
      a[ks] = *(const short8*)&As[arow * 128 + ((ks * 32 + quad * 8 + mr * 8) & 127)];
  }
  __syncthreads();                           // all frag reads done before aliasing

  // ---- stage yidx into dead As LDS ----
  {
    int Pt = Ptot[0];
    for (int t = tid; t < 576; t += 256) {
      int row = t / 9, r = t - row * 9;
      int grow = row0 + row;
      int y = -1;
      if (grow < NN) y = (r == 8) ? (Pt + grow) : pidx[grow * RR + r];
      yidxL[t] = y;
    }
  }
  __syncthreads();

  for (int r = 0; r < 9; ++r) {
    int cur = r & 1;
    if (r < 8) {                             // prefetch next W
      int n = tid >> 1, half = tid & 1;
      const uint4v* wsrc = (const uint4v*)(Wt + ((size_t)(r + 1) * 128 + n) * 128) + half * 8;
#pragma unroll
      for (int k = 0; k < 8; ++k) {
        uint4v v = wsrc[k];
        int pos = (half * 64 + k * 8 + (n & 15) * 8) & 127;
        *(uint4v*)&Ws[1 - cur][n * 128 + pos] = v;
      }
    }

    floatx4 acc[8];
#pragma unroll
    for (int ni = 0; ni < 8; ++ni) acc[ni] = (floatx4){0.f, 0.f, 0.f, 0.f};
#pragma unroll
    for (int ks = 0; ks < 4; ++ks) {
#pragma unroll
      for (int ni = 0; ni < 8; ++ni) {
        short8 b = *(const short8*)&Ws[cur][(ni * 16 + mr) * 128 +
                                            ((ks * 32 + quad * 8 + mr * 8) & 127)];
        acc[ni] = __builtin_amdgcn_mfma_f32_16x16x32_bf16(a[ks], b, acc[ni], 0, 0, 0);
      }
    }
#pragma unroll
    for (int rg = 0; rg < 4; ++rg) {
      int row = wave * 16 + quad * 4 + rg;
      int y = yidxL[row * 9 + r];
      if (y >= 0) {
        unsigned int* yr = Ypk + (size_t)y * 64;
#pragma unroll
        for (int nip = 0; nip < 4; ++nip)
          yr[nip * 16 + mr] = pk2bf(acc[2 * nip][rg], acc[2 * nip + 1][rg]);
      }
    }
    __syncthreads();
  }
}

// ---------------------------------------------------------------------------
// Aggregation: out[v] = relu(bias + Yroot[v] + sum_e s_e * Y[yrow_e]).
// 8 lanes per dst row (32 B each, 256 B/edge coalesced); software-pipelined.
// ---------------------------------------------------------------------------
__global__ __launch_bounds__(256) void aggregate(
    const unsigned int* __restrict__ Ypk,
    const int* __restrict__ rowptr,          // [NN+1]
    const int2* __restrict__ recs,           // [EE]
    const int* __restrict__ Ptot,
    const float* __restrict__ bias,          // [128]
    void* __restrict__ outp, int out_bf16)
{
  int gid = blockIdx.x * 256 + threadIdx.x;  // exactly NN*8 threads
  int v = gid >> 3, o = gid & 7;
  int c0 = 32 * (o >> 1) + 8 * (o & 1);      // lo-col base; hi at c0+16
  int Pt = Ptot[0];

  float lo[8], hi[8];
  {
    const uint4v* rp = (const uint4v*)(Ypk + (size_t)(Pt + v) * 64 + o * 8);
    uint4v u0 = rp[0], u1 = rp[1];
    unsigned um[8];
    *(uint4v*)&um[0] = u0; *(uint4v*)&um[4] = u1;
#pragma unroll
    for (int j = 0; j < 8; ++j) {
      lo[j] = bias[c0 + j] + bflo(um[j]);
      hi[j] = bias[c0 + 16 + j] + bfhi(um[j]);
    }
  }

  int beg = rowptr[v], end = rowptr[v + 1];
  if (beg < end) {
    int2 rec = recs[beg];
    const uint4v* yp = (const uint4v*)(Ypk + (size_t)rec.x * 64 + o * 8);
    uint4v c0v = yp[0], c1v = yp[1];
    for (int e = beg; e < end; ++e) {
      int2 nrec = rec;
      uint4v n0 = c0v, n1 = c1v;
      if (e + 1 < end) {
        nrec = recs[e + 1];
        const uint4v* np = (const uint4v*)(Ypk + (size_t)nrec.x * 64 + o * 8);
        n0 = np[0]; n1 = np[1];
      }
      float s = __int_as_float(rec.y);
      unsigned um[8];
      *(uint4v*)&um[0] = c0v; *(uint4v*)&um[4] = c1v;
#pragma unroll
      for (int j = 0; j < 8; ++j) {
        lo[j] = fmaf(s, bflo(um[j]), lo[j]);
        hi[j] = fmaf(s, bfhi(um[j]), hi[j]);
      }
      rec = nrec; c0v = n0; c1v = n1;
    }
  }

#pragma unroll
  for (int j = 0; j < 8; ++j) {
    lo[j] = fmaxf(lo[j], 0.f);
    hi[j] = fmaxf(hi[j], 0.f);
  }

  if (out_bf16) {
    unsigned int* h = (unsigned int*)outp;   // std rows: uint j = cols 2j|2j+1
    uint4v wl, wh;
#pragma unroll
    for (int t = 0; t < 4; ++t) {
      wl[t] = pk2bf(lo[2 * t], lo[2 * t + 1]);
      wh[t] = pk2bf(hi[2 * t], hi[2 * t + 1]);
    }
    *(uint4v*)&h[(size_t)v * 64 + c0 / 2] = wl;
    *(uint4v*)&h[(size_t)v * 64 + c0 / 2 + 8] = wh;
  } else {
    float* out = (float*)outp;
    float4* dl = (float4*)(out + (size_t)v * 128 + c0);
    float4* dh = (float4*)(out + (size_t)v * 128 + c0 + 16);
    dl[0] = make_float4(lo[0], lo[1], lo[2], lo[3]);
    dl[1] = make_float4(lo[4], lo[5], lo[6], lo[7]);
    dh[0] = make_float4(hi[0], hi[1], hi[2], hi[3]);
    dh[1] = make_float4(hi[4], hi[5], hi[6], hi[7]);
  }
}

// ---------------------------------------------------------------------------
extern "C" void kernel_launch(void* const* d_in, const int* in_sizes, int n_in,
                              void* d_out, int out_size, void* d_ws, size_t ws_size,
                              hipStream_t stream) {
  const float* x       = (const float*)d_in[0];
  const int*   ei      = (const int*)d_in[1];
  const int*   et      = (const int*)d_in[2];
  const float* rel_w1  = (const float*)d_in[3];
  const float* root_w1 = (const float*)d_in[4];
  const float* b1      = (const float*)d_in[5];
  const float* rel_w2  = (const float*)d_in[6];
  const float* root_w2 = (const float*)d_in[7];
  const float* b2      = (const float*)d_in[8];

  char* ws = (char*)d_ws;
  size_t off = 0;
  auto alloc = [&](size_t bytes) { char* p = ws + off; off = (off + bytes + 255) & ~(size_t)255; return p; };
  unsigned int*   Ypk   = (unsigned int*)alloc((size_t)(EE + NN) * 64 * 4);  // 189.4 MB worst-case
  unsigned int*   h1    = (unsigned int*)alloc((size_t)NN * 64 * 4);         // 25.6 MB
  unsigned short* Wt    = (unsigned short*)alloc((size_t)2 * 9 * DD * DD * 2);
  int*            cntd  = (int*)alloc((size_t)NN * 4);                       // contiguous counter
  int*            cntdr = (int*)alloc((size_t)K8 * 4);                       //   block for one
  int*            cntsr = (int*)alloc((size_t)K8 * 4);                       //   memset
  int*            rowptr= (int*)alloc((size_t)(NN + 1) * 4);
  int*            rowfill=(int*)alloc((size_t)NN * 4);
  int*            pidx  = (int*)alloc((size_t)K8 * 4);
  int2*           recs  = (int2*)alloc((size_t)EE * 8);                      // 5.12 MB
  int*            bsum1 = (int*)alloc((size_t)NSB1 * 4);
  int*            bbase1= (int*)alloc((size_t)NSB1 * 4);
  int*            bsum2 = (int*)alloc((size_t)NSB2 * 4);
  int*            bbase2= (int*)alloc((size_t)NSB2 * 4);
  int*            Ptot  = (int*)alloc(256);

  size_t cnt_span = (char*)cntsr + (size_t)K8 * 4 - (char*)cntd;
  hipMemsetAsync(cntd, 0, cnt_span, stream);

  w_prep_all<<<(2 * 9 * DD * DD) / 256, 256, 0, stream>>>(rel_w1, root_w1, rel_w2, root_w2, Wt);
  count_all<<<EE / 256, 256, 0, stream>>>(ei, et, cntd, cntdr, cntsr);

  scan_a<<<NSB1, 256, 0, stream>>>((const int4*)cntd, NN / 4, 0, bsum1);
  scan_b<<<1, 64, 0, stream>>>(bsum1, NSB1, bbase1, nullptr);
  scan_c<<<NSB1, 256, 0, stream>>>(cntd, bbase1, NN, 0, rowptr, rowfill);

  scan_a<<<NSB2, 256, 0, stream>>>((const int4*)cntsr, K8 / 4, 1, bsum2);
  scan_b<<<1, 64, 0, stream>>>(bsum2, NSB2, bbase2, Ptot);
  scan_c<<<NSB2, 256, 0, stream>>>(cntsr, bbase2, K8, 1, pidx, nullptr);

  place2<<<EE / 256, 256, 0, stream>>>(ei, et, cntdr, pidx, rowfill, recs);

  const int GB = (NN + 63) / 64;   // 1563
  const int AB = (NN * 8) / 256;   // 3125

  gemm_y<<<GB, 256, 0, stream>>>(x, 1, Wt, pidx, Ptot, Ypk);
  aggregate<<<AB, 256, 0, stream>>>(Ypk, rowptr, recs, Ptot, b1, h1, 1);
  gemm_y<<<GB, 256, 0, stream>>>(h1, 0, Wt + (size_t)9 * DD * DD, pidx, Ptot, Ypk);
  aggregate<<<AB, 256, 0, stream>>>(Ypk, rowptr, recs, Ptot, b2, d_out, 0);
}

// Round 7
// 475.998 us; speedup vs baseline: 1.0759x; 1.0759x over previous
//
#include <hip/hip_runtime.h>
#include <hip/hip_bf16.h>

#define NN 100000
#define EE 640000
#define DD 128
#define RR 8
#define K8 (NN * RR)      // 800000 (src,rel) pair keys
#define NSB1 25           // ceil(NN/4096)
#define NSB2 196          // ceil(K8/4096)

typedef __attribute__((ext_vector_type(8))) short short8;
typedef __attribute__((ext_vector_type(4))) float floatx4;
typedef __attribute__((ext_vector_type(4))) unsigned int uint4v;

__device__ __forceinline__ unsigned short f2bf(float f) {
  unsigned int u = __float_as_uint(f);
  u += 0x7FFFu + ((u >> 16) & 1u);   // RNE
  return (unsigned short)(u >> 16);
}
__device__ __forceinline__ unsigned int pk2bf(float a, float b) {
  __hip_bfloat162 h = __float22bfloat162_rn(make_float2(a, b));
  unsigned int u;
  __builtin_memcpy(&u, &h, 4);
  return u;                          // low16 = a, high16 = b
}
__device__ __forceinline__ float bflo(unsigned int u) { return __uint_as_float(u << 16); }
__device__ __forceinline__ float bfhi(unsigned int u) { return __uint_as_float(u & 0xFFFF0000u); }

// ---------------------------------------------------------------------------
// Both layers' weights: wt[set][r][n][k] = bf16(W[k][n]); r=8 is root.
// ---------------------------------------------------------------------------
__global__ __launch_bounds__(256) void w_prep_all(
    const float* __restrict__ rel1, const float* __restrict__ root1,
    const float* __restrict__ rel2, const float* __restrict__ root2,
    unsigned short* __restrict__ wt)
{
  int id = blockIdx.x * 256 + threadIdx.x;       // [0, 2*9*16384)
  int set = id >= 147456;
  int rem = id - set * 147456;
  int r = rem >> 14, n = (rem >> 7) & 127, k = rem & 127;
  const float* rel = set ? rel2 : rel1;
  const float* root = set ? root2 : root1;
  float v = (r < RR) ? rel[((size_t)r * DD + k) * DD + n] : root[(size_t)k * DD + n];
  wt[id] = f2bf(v);
}

// ---------------------------------------------------------------------------
// Counts: per-dst degree, per-(dst,r) degree (scale), per-(src,r) usage.
// ---------------------------------------------------------------------------
__global__ __launch_bounds__(256) void count_all(
    const int* __restrict__ ei, const int* __restrict__ et,
    int* __restrict__ cntd, int* __restrict__ cntdr, int* __restrict__ cntsr)
{
  int e = blockIdx.x * 256 + threadIdx.x;
  int src = ei[e], dst = ei[EE + e], r = et[e];
  atomicAdd(&cntd[dst], 1);
  atomicAdd(&cntdr[dst * RR + r], 1);
  atomicAdd(&cntsr[src * RR + r], 1);
}

// ---------------------------------------------------------------------------
// Generic 3-phase exclusive scan. mode 0: sum values; mode 1: count nonzero.
// ---------------------------------------------------------------------------
__global__ __launch_bounds__(256) void scan_a(
    const int4* __restrict__ c4, int n4, int mode, int* __restrict__ bsum)
{
  int t = threadIdx.x;
  int s = 0;
#pragma unroll
  for (int i = 0; i < 4; ++i) {
    int idx = blockIdx.x * 1024 + i * 256 + t;
    if (idx < n4) {
      int4 v = c4[idx];
      if (mode) s += (v.x > 0) + (v.y > 0) + (v.z > 0) + (v.w > 0);
      else      s += v.x + v.y + v.z + v.w;
    }
  }
  __shared__ int wsum[4];
  for (int d = 32; d; d >>= 1) s += __shfl_xor(s, d, 64);
  if ((t & 63) == 0) wsum[t >> 6] = s;
  __syncthreads();
  if (t == 0) bsum[blockIdx.x] = wsum[0] + wsum[1] + wsum[2] + wsum[3];
}

__global__ void scan_b(const int* __restrict__ bsum, int nsb,
                       int* __restrict__ bbase, int* __restrict__ tot)
{
  int lane = threadIdx.x;                         // 64 threads
  int v[4]; int s = 0;
#pragma unroll
  for (int i = 0; i < 4; ++i) {
    int idx = lane * 4 + i;
    v[i] = (idx < nsb) ? bsum[idx] : 0; s += v[i];
  }
  int inc = s;
  for (int d = 1; d < 64; d <<= 1) {
    int o = __shfl_up(inc, d, 64);
    if (lane >= d) inc += o;
  }
  int running = inc - s;
#pragma unroll
  for (int i = 0; i < 4; ++i) {
    int idx = lane * 4 + i;
    if (idx < nsb) { bbase[idx] = running; running += v[i]; }
  }
  if (lane == 63 && tot != nullptr) tot[0] = inc;
}

// mode 0: out0=rowptr (and out0[n]=EE by block0), out1=rowfill.
// mode 1: out0=pidx (compact index or -1).
__global__ __launch_bounds__(256) void scan_c(
    const int* __restrict__ cnt, const int* __restrict__ bbase, int n, int mode,
    int* __restrict__ out0, int* __restrict__ out1)
{
  int t = threadIdx.x;
  int base = blockIdx.x * 4096 + t * 16;
  int v[16]; int s = 0;
#pragma unroll
  for (int i = 0; i < 16; ++i) {
    int idx = base + i;
    v[i] = (idx < n) ? cnt[idx] : 0;
    s += mode ? (v[i] > 0) : v[i];
  }
  int lane = t & 63, wid = t >> 6;
  int inc = s;
  for (int d = 1; d < 64; d <<= 1) {
    int o = __shfl_up(inc, d, 64);
    if (lane >= d) inc += o;
  }
  __shared__ int wsum[4];
  if (lane == 63) wsum[wid] = inc;
  __syncthreads();
  int wb = 0;
  for (int w = 0; w < wid; ++w) wb += wsum[w];
  int running = bbase[blockIdx.x] + wb + (inc - s);
#pragma unroll
  for (int i = 0; i < 16; ++i) {
    int idx = base + i;
    if (idx < n) {
      if (mode) { out0[idx] = (v[i] > 0) ? running : -1; running += (v[i] > 0); }
      else      { out0[idx] = running; out1[idx] = running; running += v[i]; }
    }
  }
  if (!mode && blockIdx.x == 0 && t == 0) out0[n] = EE;
}

// ---------------------------------------------------------------------------
// Place edges into dst-major CSR: rec = (compact yrow of (src,r), scale(dst,r))
// ---------------------------------------------------------------------------
__global__ __launch_bounds__(256) void place2(
    const int* __restrict__ ei, const int* __restrict__ et,
    const int* __restrict__ cntdr, const int* __restrict__ pidx,
    int* __restrict__ rowfill, int2* __restrict__ recs)
{
  int e = blockIdx.x * 256 + threadIdx.x;
  int src = ei[e], dst = ei[EE + e], r = et[e];
  int slot = atomicAdd(&rowfill[dst], 1);
  float s = 1.0f / (float)max(cntdr[dst * RR + r], 1);
  int2 rec; rec.x = pidx[src * RR + r]; rec.y = __float_as_int(s);
  recs[slot] = rec;
}

// ---------------------------------------------------------------------------
// GEMM: per 64-row tile, 9 rounds r: Y[yrow(v,r)] = bf16(Xv @ W_r), stored
// only if pair used (root r=8 at Ptot+v). BARRIER-FREE K-loop: B fragments
// loaded directly from global W (L2-resident, each tile read once per block:
// wave w owns n-cols [32w,32w+32)); A frags register-resident (4 m-tiles).
// Stores never drained mid-loop -> full cross-round pipelining.
// ---------------------------------------------------------------------------
__global__ __launch_bounds__(256, 3) void gemm_y(
    const void* __restrict__ Xin, int in_f32,
    const unsigned short* __restrict__ Wt,   // [9][128][128] bf16 [r][n][k]
    const int* __restrict__ pidx,            // [K8]
    const int* __restrict__ Ptot,            // [1]
    unsigned int* __restrict__ Ypk)
{
  __shared__ unsigned short As[64 * 128];    // 16 KB
  __shared__ int yidxL[576];                 // 2.25 KB
  const int tid = threadIdx.x;
  const int row0 = blockIdx.x * 64;
  const int wave = tid >> 6, lane = tid & 63;
  const int quad = lane >> 4, mr = lane & 15;

  // ---- stage A (rotated by (row&15)*8 shorts) ----
  {
    int row = tid >> 2, q = tid & 3, grow = row0 + row;
    if (in_f32) {
      const float4* xs = (const float4*)((const float*)Xin + (size_t)grow * 128 + q * 32);
#pragma unroll
      for (int c = 0; c < 4; ++c) {
        uint4v v = {0u, 0u, 0u, 0u};
        if (grow < NN) {
          float4 va = xs[c * 2], vb = xs[c * 2 + 1];
          v[0] = pk2bf(va.x, va.y); v[1] = pk2bf(va.z, va.w);
          v[2] = pk2bf(vb.x, vb.y); v[3] = pk2bf(vb.z, vb.w);
        }
        int pos = (q * 32 + c * 8 + (row & 15) * 8) & 127;
        *(uint4v*)&As[row * 128 + pos] = v;
      }
    } else {
      const uint4v* xs = (const uint4v*)((const unsigned int*)Xin + (size_t)grow * 64 + q * 16);
#pragma unroll
      for (int c = 0; c < 4; ++c) {
        uint4v v = (grow < NN) ? xs[c] : (uint4v){0u, 0u, 0u, 0u};
        int pos = (q * 32 + c * 8 + (row & 15) * 8) & 127;
        *(uint4v*)&As[row * 128 + pos] = v;
      }
    }
  }
  // ---- stage yidx ----
  {
    int Pt = Ptot[0];
    for (int t = tid; t < 576; t += 256) {
      int row = t / 9, r = t - row * 9;
      int grow = row0 + row;
      int y = -1;
      if (grow < NN) y = (r == 8) ? (Pt + grow) : pidx[grow * RR + r];
      yidxL[t] = y;
    }
  }
  __syncthreads();

  // ---- A fragments: 4 m-tiles x 4 k-steps, register-resident (64 VGPR) ----
  short8 a[4][4];
#pragma unroll
  for (int mi = 0; mi < 4; ++mi)
#pragma unroll
    for (int ks = 0; ks < 4; ++ks)
      a[mi][ks] = *(const short8*)&As[(mi * 16 + mr) * 128 +
                                      ((ks * 32 + quad * 8 + mr * 8) & 127)];

  // ---- barrier-free rounds ----
  const unsigned short* wbase = Wt + (size_t)(wave * 32 + mr) * 128 + quad * 8;
  for (int r = 0; r < 9; ++r) {
    const unsigned short* wr = wbase + (size_t)r * 16384;
    floatx4 acc[4][2];
#pragma unroll
    for (int mi = 0; mi < 4; ++mi) {
      acc[mi][0] = (floatx4){0.f, 0.f, 0.f, 0.f};
      acc[mi][1] = (floatx4){0.f, 0.f, 0.f, 0.f};
    }
#pragma unroll
    for (int ks = 0; ks < 4; ++ks) {
      short8 b0 = *(const short8*)(wr + ks * 32);            // n = wave*32+mr
      short8 b1 = *(const short8*)(wr + 16 * 128 + ks * 32); // n = wave*32+16+mr
#pragma unroll
      for (int mi = 0; mi < 4; ++mi) {
        acc[mi][0] = __builtin_amdgcn_mfma_f32_16x16x32_bf16(a[mi][ks], b0, acc[mi][0], 0, 0, 0);
        acc[mi][1] = __builtin_amdgcn_mfma_f32_16x16x32_bf16(a[mi][ks], b1, acc[mi][1], 0, 0, 0);
      }
    }
    // packed store: uint (wave*16+mr) of row y covers cols 32w+mr, 32w+16+mr
#pragma unroll
    for (int mi = 0; mi < 4; ++mi) {
#pragma unroll
      for (int rg = 0; rg < 4; ++rg) {
        int row = mi * 16 + quad * 4 + rg;
        int y = yidxL[row * 9 + r];
        if (y >= 0)
          Ypk[(size_t)y * 64 + wave * 16 + mr] = pk2bf(acc[mi][0][rg], acc[mi][1][rg]);
      }
    }
  }
}

// ---------------------------------------------------------------------------
// Aggregation: out[v] = relu(bias + Yroot[v] + sum_e s_e * Y[yrow_e]).
// 8 lanes per dst row (32 B each, 256 B/edge coalesced); software-pipelined.
// ---------------------------------------------------------------------------
__global__ __launch_bounds__(256) void aggregate(
    const unsigned int* __restrict__ Ypk,
    const int* __restrict__ rowptr,          // [NN+1]
    const int2* __restrict__ recs,           // [EE]
    const int* __restrict__ Ptot,
    const float* __restrict__ bias,          // [128]
    void* __restrict__ outp, int out_bf16)
{
  int gid = blockIdx.x * 256 + threadIdx.x;  // exactly NN*8 threads
  int v = gid >> 3, o = gid & 7;
  int c0 = 32 * (o >> 1) + 8 * (o & 1);      // lo-col base; hi at c0+16
  int Pt = Ptot[0];

  float lo[8], hi[8];
  {
    const uint4v* rp = (const uint4v*)(Ypk + (size_t)(Pt + v) * 64 + o * 8);
    uint4v u0 = rp[0], u1 = rp[1];
    unsigned um[8];
    *(uint4v*)&um[0] = u0; *(uint4v*)&um[4] = u1;
#pragma unroll
    for (int j = 0; j < 8; ++j) {
      lo[j] = bias[c0 + j] + bflo(um[j]);
      hi[j] = bias[c0 + 16 + j] + bfhi(um[j]);
    }
  }

  int beg = rowptr[v], end = rowptr[v + 1];
  if (beg < end) {
    int2 rec = recs[beg];
    const uint4v* yp = (const uint4v*)(Ypk + (size_t)rec.x * 64 + o * 8);
    uint4v c0v = yp[0], c1v = yp[1];
    for (int e = beg; e < end; ++e) {
      int2 nrec = rec;
      uint4v n0 = c0v, n1 = c1v;
      if (e + 1 < end) {
        nrec = recs[e + 1];
        const uint4v* np = (const uint4v*)(Ypk + (size_t)nrec.x * 64 + o * 8);
        n0 = np[0]; n1 = np[1];
      }
      float s = __int_as_float(rec.y);
      unsigned um[8];
      *(uint4v*)&um[0] = c0v; *(uint4v*)&um[4] = c1v;
#pragma unroll
      for (int j = 0; j < 8; ++j) {
        lo[j] = fmaf(s, bflo(um[j]), lo[j]);
        hi[j] = fmaf(s, bfhi(um[j]), hi[j]);
      }
      rec = nrec; c0v = n0; c1v = n1;
    }
  }

#pragma unroll
  for (int j = 0; j < 8; ++j) {
    lo[j] = fmaxf(lo[j], 0.f);
    hi[j] = fmaxf(hi[j], 0.f);
  }

  if (out_bf16) {
    unsigned int* h = (unsigned int*)outp;   // std rows: uint j = cols 2j|2j+1
    uint4v wl, wh;
#pragma unroll
    for (int t = 0; t < 4; ++t) {
      wl[t] = pk2bf(lo[2 * t], lo[2 * t + 1]);
      wh[t] = pk2bf(hi[2 * t], hi[2 * t + 1]);
    }
    *(uint4v*)&h[(size_t)v * 64 + c0 / 2] = wl;
    *(uint4v*)&h[(size_t)v * 64 + c0 / 2 + 8] = wh;
  } else {
    float* out = (float*)outp;
    float4* dl = (float4*)(out + (size_t)v * 128 + c0);
    float4* dh = (float4*)(out + (size_t)v * 128 + c0 + 16);
    dl[0] = make_float4(lo[0], lo[1], lo[2], lo[3]);
    dl[1] = make_float4(lo[4], lo[5], lo[6], lo[7]);
    dh[0] = make_float4(hi[0], hi[1], hi[2], hi[3]);
    dh[1] = make_float4(hi[4], hi[5], hi[6], hi[7]);
  }
}

// ---------------------------------------------------------------------------
extern "C" void kernel_launch(void* const* d_in, const int* in_sizes, int n_in,
                              void* d_out, int out_size, void* d_ws, size_t ws_size,
                              hipStream_t stream) {
  const float* x       = (const float*)d_in[0];
  const int*   ei      = (const int*)d_in[1];
  const int*   et      = (const int*)d_in[2];
  const float* rel_w1  = (const float*)d_in[3];
  const float* root_w1 = (const float*)d_in[4];
  const float* b1      = (const float*)d_in[5];
  const float* rel_w2  = (const float*)d_in[6];
  const float* root_w2 = (const float*)d_in[7];
  const float* b2      = (const float*)d_in[8];

  char* ws = (char*)d_ws;
  size_t off = 0;
  auto alloc = [&](size_t bytes) { char* p = ws + off; off = (off + bytes + 255) & ~(size_t)255; return p; };
  unsigned int*   Ypk   = (unsigned int*)alloc((size_t)(EE + NN) * 64 * 4);  // 189.4 MB worst-case
  unsigned int*   h1    = (unsigned int*)alloc((size_t)NN * 64 * 4);         // 25.6 MB
  unsigned short* Wt    = (unsigned short*)alloc((size_t)2 * 9 * DD * DD * 2);
  int*            cntd  = (int*)alloc((size_t)NN * 4);                       // contiguous counter
  int*            cntdr = (int*)alloc((size_t)K8 * 4);                       //   block for one
  int*            cntsr = (int*)alloc((size_t)K8 * 4);                       //   memset
  int*            rowptr= (int*)alloc((size_t)(NN + 1) * 4);
  int*            rowfill=(int*)alloc((size_t)NN * 4);
  int*            pidx  = (int*)alloc((size_t)K8 * 4);
  int2*           recs  = (int2*)alloc((size_t)EE * 8);                      // 5.12 MB
  int*            bsum1 = (int*)alloc((size_t)NSB1 * 4);
  int*            bbase1= (int*)alloc((size_t)NSB1 * 4);
  int*            bsum2 = (int*)alloc((size_t)NSB2 * 4);
  int*            bbase2= (int*)alloc((size_t)NSB2 * 4);
  int*            Ptot  = (int*)alloc(256);

  size_t cnt_span = (char*)cntsr + (size_t)K8 * 4 - (char*)cntd;
  hipMemsetAsync(cntd, 0, cnt_span, stream);

  w_prep_all<<<(2 * 9 * DD * DD) / 256, 256, 0, stream>>>(rel_w1, root_w1, rel_w2, root_w2, Wt);
  count_all<<<EE / 256, 256, 0, stream>>>(ei, et, cntd, cntdr, cntsr);

  scan_a<<<NSB1, 256, 0, stream>>>((const int4*)cntd, NN / 4, 0, bsum1);
  scan_b<<<1, 64, 0, stream>>>(bsum1, NSB1, bbase1, nullptr);
  scan_c<<<NSB1, 256, 0, stream>>>(cntd, bbase1, NN, 0, rowptr, rowfill);

  scan_a<<<NSB2, 256, 0, stream>>>((const int4*)cntsr, K8 / 4, 1, bsum2);
  scan_b<<<1, 64, 0, stream>>>(bsum2, NSB2, bbase2, Ptot);
  scan_c<<<NSB2, 256, 0, stream>>>(cntsr, bbase2, K8, 1, pidx, nullptr);

  place2<<<EE / 256, 256, 0, stream>>>(ei, et, cntdr, pidx, rowfill, recs);

  const int GB = (NN + 63) / 64;   // 1563
  const int AB = (NN * 8) / 256;   // 3125

  gemm_y<<<GB, 256, 0, stream>>>(x, 1, Wt, pidx, Ptot, Ypk);
  aggregate<<<AB, 256, 0, stream>>>(Ypk, rowptr, recs, Ptot, b1, h1, 1);
  gemm_y<<<GB, 256, 0, stream>>>(h1, 0, Wt + (size_t)9 * DD * DD, pidx, Ptot, Ypk);
  aggregate<<<AB, 256, 0, stream>>>(Ypk, rowptr, recs, Ptot, b2, d_out, 0);
}

// Round 8
// 436.199 us; speedup vs baseline: 1.1741x; 1.0912x over previous
//
#include <hip/hip_runtime.h>
#include <hip/hip_bf16.h>

#define NN 100000
#define EE 640000
#define DD 128
#define RR 8
#define K8 (NN * RR)      // 800000 (rel,src) pair keys, key = r*NN + src
#define NSB1 25           // ceil(NN/4096)
#define NSB2 196          // ceil(K8/4096)
#define GBMAX 11571       // worst-case gemm blocks: (640000+8*63+100032)/64

typedef __attribute__((ext_vector_type(8))) short short8;
typedef __attribute__((ext_vector_type(4))) float floatx4;
typedef __attribute__((ext_vector_type(4))) unsigned int uint4v;

__device__ __forceinline__ unsigned short f2bf(float f) {
  unsigned int u = __float_as_uint(f);
  u += 0x7FFFu + ((u >> 16) & 1u);   // RNE
  return (unsigned short)(u >> 16);
}
__device__ __forceinline__ unsigned int pk2bf(float a, float b) {
  __hip_bfloat162 h = __float22bfloat162_rn(make_float2(a, b));
  unsigned int u;
  __builtin_memcpy(&u, &h, 4);
  return u;                          // low16 = a, high16 = b
}
__device__ __forceinline__ float bflo(unsigned int u) { return __uint_as_float(u << 16); }
__device__ __forceinline__ float bfhi(unsigned int u) { return __uint_as_float(u & 0xFFFF0000u); }

// ---------------------------------------------------------------------------
// x (fp32 [NN][128]) -> Xb (bf16 std rows as uints: uint j = cols 2j|2j+1<<16)
// ---------------------------------------------------------------------------
__global__ __launch_bounds__(256) void xb_prep(
    const float* __restrict__ x, unsigned int* __restrict__ xb)
{
  int g = blockIdx.x * 256 + threadIdx.x;        // NN*16 threads? -> NN*16/... use 16/row
  int v = g >> 4, seg = g & 15;
  const float4* s4 = (const float4*)(x + (size_t)v * 128 + seg * 8);
  float4 a = s4[0], b = s4[1];
  uint4v o;
  o[0] = pk2bf(a.x, a.y); o[1] = pk2bf(a.z, a.w);
  o[2] = pk2bf(b.x, b.y); o[3] = pk2bf(b.z, b.w);
  *(uint4v*)(xb + (size_t)v * 64 + seg * 4) = o;
}

// ---------------------------------------------------------------------------
// Both layers' weights: wt[set][r][n][k] = bf16(W[k][n]); r=8 is root.
// ---------------------------------------------------------------------------
__global__ __launch_bounds__(256) void w_prep_all(
    const float* __restrict__ rel1, const float* __restrict__ root1,
    const float* __restrict__ rel2, const float* __restrict__ root2,
    unsigned short* __restrict__ wt)
{
  int id = blockIdx.x * 256 + threadIdx.x;       // [0, 2*9*16384)
  int set = id >= 147456;
  int rem = id - set * 147456;
  int r = rem >> 14, n = (rem >> 7) & 127, k = rem & 127;
  const float* rel = set ? rel2 : rel1;
  const float* root = set ? root2 : root1;
  float v = (r < RR) ? rel[((size_t)r * DD + k) * DD + n] : root[(size_t)k * DD + n];
  wt[id] = f2bf(v);
}

// ---------------------------------------------------------------------------
// Counts: per-dst degree, per-(dst,r) degree (scale), per-(r,src) usage.
// ---------------------------------------------------------------------------
__global__ __launch_bounds__(256) void count_all(
    const int* __restrict__ ei, const int* __restrict__ et,
    int* __restrict__ cntd, int* __restrict__ cntdr, int* __restrict__ cntsr)
{
  int e = blockIdx.x * 256 + threadIdx.x;
  int src = ei[e], dst = ei[EE + e], r = et[e];
  atomicAdd(&cntd[dst], 1);
  atomicAdd(&cntdr[dst * RR + r], 1);
  atomicAdd(&cntsr[r * NN + src], 1);
}

// ---------------------------------------------------------------------------
// Generic 3-phase exclusive scan. mode 0: sum values; mode 1: count nonzero.
// ---------------------------------------------------------------------------
__global__ __launch_bounds__(256) void scan_a(
    const int4* __restrict__ c4, int n4, int mode, int* __restrict__ bsum)
{
  int t = threadIdx.x;
  int s = 0;
#pragma unroll
  for (int i = 0; i < 4; ++i) {
    int idx = blockIdx.x * 1024 + i * 256 + t;
    if (idx < n4) {
      int4 v = c4[idx];
      if (mode) s += (v.x > 0) + (v.y > 0) + (v.z > 0) + (v.w > 0);
      else      s += v.x + v.y + v.z + v.w;
    }
  }
  __shared__ int wsum[4];
  for (int d = 32; d; d >>= 1) s += __shfl_xor(s, d, 64);
  if ((t & 63) == 0) wsum[t >> 6] = s;
  __syncthreads();
  if (t == 0) bsum[blockIdx.x] = wsum[0] + wsum[1] + wsum[2] + wsum[3];
}

__global__ void scan_b(const int* __restrict__ bsum, int nsb,
                       int* __restrict__ bbase, int* __restrict__ tot)
{
  int lane = threadIdx.x;                         // 64 threads
  int v[4]; int s = 0;
#pragma unroll
  for (int i = 0; i < 4; ++i) {
    int idx = lane * 4 + i;
    v[i] = (idx < nsb) ? bsum[idx] : 0; s += v[i];
  }
  int inc = s;
  for (int d = 1; d < 64; d <<= 1) {
    int o = __shfl_up(inc, d, 64);
    if (lane >= d) inc += o;
  }
  int running = inc - s;
#pragma unroll
  for (int i = 0; i < 4; ++i) {
    int idx = lane * 4 + i;
    if (idx < nsb) { bbase[idx] = running; running += v[i]; }
  }
  if (lane == 63 && tot != nullptr) tot[0] = inc;
}

// mode 0: out0=rowptr (+out0[n]=EE), out1=rowfill.
// mode 1: out0=raw grank or -1; also writes ubp[r]=rank at key r*NN.
__global__ __launch_bounds__(256) void scan_c(
    const int* __restrict__ cnt, const int* __restrict__ bbase, int n, int mode,
    int* __restrict__ out0, int* __restrict__ out1, int* __restrict__ ubp)
{
  int t = threadIdx.x;
  int base = blockIdx.x * 4096 + t * 16;
  int v[16]; int s = 0;
#pragma unroll
  for (int i = 0; i < 16; ++i) {
    int idx = base + i;
    v[i] = (idx < n) ? cnt[idx] : 0;
    s += mode ? (v[i] > 0) : v[i];
  }
  int lane = t & 63, wid = t >> 6;
  int inc = s;
  for (int d = 1; d < 64; d <<= 1) {
    int o = __shfl_up(inc, d, 64);
    if (lane >= d) inc += o;
  }
  __shared__ int wsum[4];
  if (lane == 63) wsum[wid] = inc;
  __syncthreads();
  int wb = 0;
  for (int w = 0; w < wid; ++w) wb += wsum[w];
  int running = bbase[blockIdx.x] + wb + (inc - s);
#pragma unroll
  for (int i = 0; i < 16; ++i) {
    int idx = base + i;
    if (idx < n) {
      if (mode) {
        if (idx % NN == 0) ubp[idx / NN] = running;
        out0[idx] = (v[i] > 0) ? running : -1;
        running += (v[i] > 0);
      } else {
        out0[idx] = running; out1[idx] = running; running += v[i];
      }
    }
  }
  if (!mode && blockIdx.x == 0 && t == 0) out0[n] = EE;
}

// ---------------------------------------------------------------------------
// pb[r]: 64-padded base of relation r's Y region; pb[8]=root base; pb[9]=end.
// ---------------------------------------------------------------------------
__global__ void pb_kernel(const int* __restrict__ ub, const int* __restrict__ tot,
                          int* __restrict__ pb)
{
  if (threadIdx.x == 0) {
    int base = 0;
    for (int r = 0; r < RR; ++r) {
      pb[r] = base;
      int hi = (r == RR - 1) ? tot[0] : ub[r + 1];
      int u = hi - ub[r];
      base += (u + 63) & ~63;
    }
    pb[8] = base;
    pb[9] = base + ((NN + 63) & ~63);
  }
}

// remap raw grank -> final yrow = pb[r] + (grank - ub[r]); fill ysrc.
__global__ __launch_bounds__(256) void fix_kernel(
    int* __restrict__ pidx, const int* __restrict__ ub,
    const int* __restrict__ pb, int* __restrict__ ysrc)
{
  int key = blockIdx.x * 256 + threadIdx.x;      // [0, K8)
  int g = pidx[key];
  if (g < 0) return;
  int r = key / NN, src = key - r * NN;
  int y = pb[r] + (g - ub[r]);
  pidx[key] = y;
  ysrc[y] = src;
}

// ---------------------------------------------------------------------------
// Place edges into dst-major CSR: rec = (yrow of (r,src), scale(dst,r))
// ---------------------------------------------------------------------------
__global__ __launch_bounds__(256) void place2(
    const int* __restrict__ ei, const int* __restrict__ et,
    const int* __restrict__ cntdr, const int* __restrict__ pidx,
    int* __restrict__ rowfill, int2* __restrict__ recs)
{
  int e = blockIdx.x * 256 + threadIdx.x;
  int src = ei[e], dst = ei[EE + e], r = et[e];
  int slot = atomicAdd(&rowfill[dst], 1);
  float s = 1.0f / (float)max(cntdr[dst * RR + r], 1);
  int2 rec; rec.x = pidx[r * NN + src]; rec.y = __float_as_int(s);
  recs[slot] = rec;
}

// ---------------------------------------------------------------------------
// GEMM (relation-major Y): block owns 64 consecutive Y rows, one uniform W_r.
// Gather 64 src rows of Xb -> LDS (rotated); single MFMA round; DENSE
// unconditional sequential 16KB store. No multi-round store/load interleave.
// ---------------------------------------------------------------------------
__global__ __launch_bounds__(256, 3) void gemm_y(
    const unsigned int* __restrict__ Xb,     // [NN][64] std bf16 rows
    const unsigned short* __restrict__ Wt,   // [9][128][128] bf16 [r][n][k]
    const int* __restrict__ ysrc,            // [<=640504] src per yrow (r<8)
    const int* __restrict__ pb,              // [10]
    unsigned int* __restrict__ Ypk)
{
  const int yrow0 = blockIdx.x * 64;
  if (yrow0 >= pb[9]) return;
  int r = 8;
#pragma unroll
  for (int rr = 0; rr < 8; ++rr) if (yrow0 < pb[rr + 1]) { r = rr; break; }

  __shared__ unsigned short As[64 * 128];    // 16 KB
  const int tid = threadIdx.x;
  const int wave = tid >> 6, lane = tid & 63;
  const int quad = lane >> 4, mr = lane & 15;
  const int pb8 = pb[8];

  // ---- gather A rows (rotated by (row&15)*8 shorts) ----
  {
    int row = tid >> 2, q = tid & 3;
    int yrow = yrow0 + row;
    int src;
    if (r < RR) src = ysrc[yrow];            // pad rows -> 0 (memset), harmless
    else { src = yrow - pb8; if (src >= NN) src = 0; }
    const uint4v* xs = (const uint4v*)(Xb + (size_t)src * 64 + q * 16);
#pragma unroll
    for (int c = 0; c < 4; ++c) {
      uint4v v = xs[c];
      int pos = (q * 32 + c * 8 + (row & 15) * 8) & 127;
      *(uint4v*)&As[row * 128 + pos] = v;
    }
  }
  // ---- B fragments direct from L2 (wave owns n-cols [32w, 32w+32)) ----
  const unsigned short* wr = Wt + (size_t)r * 16384 + (size_t)(wave * 32 + mr) * 128 + quad * 8;
  short8 b0[4], b1[4];
#pragma unroll
  for (int ks = 0; ks < 4; ++ks) {
    b0[ks] = *(const short8*)(wr + ks * 32);
    b1[ks] = *(const short8*)(wr + 16 * 128 + ks * 32);
  }
  __syncthreads();

  floatx4 acc[4][2];
#pragma unroll
  for (int mi = 0; mi < 4; ++mi) {
    acc[mi][0] = (floatx4){0.f, 0.f, 0.f, 0.f};
    acc[mi][1] = (floatx4){0.f, 0.f, 0.f, 0.f};
  }
#pragma unroll
  for (int ks = 0; ks < 4; ++ks) {
    short8 a[4];
#pragma unroll
    for (int mi = 0; mi < 4; ++mi)
      a[mi] = *(const short8*)&As[(mi * 16 + mr) * 128 +
                                  ((ks * 32 + quad * 8 + mr * 8) & 127)];
#pragma unroll
    for (int mi = 0; mi < 4; ++mi) {
      acc[mi][0] = __builtin_amdgcn_mfma_f32_16x16x32_bf16(a[mi], b0[ks], acc[mi][0], 0, 0, 0);
      acc[mi][1] = __builtin_amdgcn_mfma_f32_16x16x32_bf16(a[mi], b1[ks], acc[mi][1], 0, 0, 0);
    }
  }
  // ---- dense store: uint (wave*16+mr) of yrow covers cols 32w+mr, 32w+16+mr
#pragma unroll
  for (int mi = 0; mi < 4; ++mi)
#pragma unroll
    for (int rg = 0; rg < 4; ++rg)
      Ypk[(size_t)(yrow0 + mi * 16 + quad * 4 + rg) * 64 + wave * 16 + mr] =
          pk2bf(acc[mi][0][rg], acc[mi][1][rg]);
}

// ---------------------------------------------------------------------------
// Aggregation: out[v] = relu(bias + Yroot[v] + sum_e s_e * Y[yrow_e]).
// 8 lanes per dst row (32 B each, 256 B/edge coalesced); software-pipelined.
// ---------------------------------------------------------------------------
__global__ __launch_bounds__(256) void aggregate(
    const unsigned int* __restrict__ Ypk,
    const int* __restrict__ rowptr,          // [NN+1]
    const int2* __restrict__ recs,           // [EE]
    const int* __restrict__ pb,
    const float* __restrict__ bias,          // [128]
    void* __restrict__ outp, int out_bf16)
{
  int gid = blockIdx.x * 256 + threadIdx.x;  // exactly NN*8 threads
  int v = gid >> 3, o = gid & 7;
  int c0 = 32 * (o >> 1) + 8 * (o & 1);      // lo-col base; hi at c0+16
  int pb8 = pb[8];

  float lo[8], hi[8];
  {
    const uint4v* rp = (const uint4v*)(Ypk + (size_t)(pb8 + v) * 64 + o * 8);
    uint4v u0 = rp[0], u1 = rp[1];
    unsigned um[8];
    *(uint4v*)&um[0] = u0; *(uint4v*)&um[4] = u1;
#pragma unroll
    for (int j = 0; j < 8; ++j) {
      lo[j] = bias[c0 + j] + bflo(um[j]);
      hi[j] = bias[c0 + 16 + j] + bfhi(um[j]);
    }
  }

  int beg = rowptr[v], end = rowptr[v + 1];
  if (beg < end) {
    int2 rec = recs[beg];
    const uint4v* yp = (const uint4v*)(Ypk + (size_t)rec.x * 64 + o * 8);
    uint4v c0v = yp[0], c1v = yp[1];
    for (int e = beg; e < end; ++e) {
      int2 nrec = rec;
      uint4v n0 = c0v, n1 = c1v;
      if (e + 1 < end) {
        nrec = recs[e + 1];
        const uint4v* np = (const uint4v*)(Ypk + (size_t)nrec.x * 64 + o * 8);
        n0 = np[0]; n1 = np[1];
      }
      float s = __int_as_float(rec.y);
      unsigned um[8];
      *(uint4v*)&um[0] = c0v; *(uint4v*)&um[4] = c1v;
#pragma unroll
      for (int j = 0; j < 8; ++j) {
        lo[j] = fmaf(s, bflo(um[j]), lo[j]);
        hi[j] = fmaf(s, bfhi(um[j]), hi[j]);
      }
      rec = nrec; c0v = n0; c1v = n1;
    }
  }

#pragma unroll
  for (int j = 0; j < 8; ++j) {
    lo[j] = fmaxf(lo[j], 0.f);
    hi[j] = fmaxf(hi[j], 0.f);
  }

  if (out_bf16) {
    unsigned int* h = (unsigned int*)outp;   // std rows: uint j = cols 2j|2j+1
    uint4v wl, wh;
#pragma unroll
    for (int t = 0; t < 4; ++t) {
      wl[t] = pk2bf(lo[2 * t], lo[2 * t + 1]);
      wh[t] = pk2bf(hi[2 * t], hi[2 * t + 1]);
    }
    *(uint4v*)&h[(size_t)v * 64 + c0 / 2] = wl;
    *(uint4v*)&h[(size_t)v * 64 + c0 / 2 + 8] = wh;
  } else {
    float* out = (float*)outp;
    float4* dl = (float4*)(out + (size_t)v * 128 + c0);
    float4* dh = (float4*)(out + (size_t)v * 128 + c0 + 16);
    dl[0] = make_float4(lo[0], lo[1], lo[2], lo[3]);
    dl[1] = make_float4(lo[4], lo[5], lo[6], lo[7]);
    dh[0] = make_float4(hi[0], hi[1], hi[2], hi[3]);
    dh[1] = make_float4(hi[4], hi[5], hi[6], hi[7]);
  }
}

// ---------------------------------------------------------------------------
extern "C" void kernel_launch(void* const* d_in, const int* in_sizes, int n_in,
                              void* d_out, int out_size, void* d_ws, size_t ws_size,
                              hipStream_t stream) {
  const float* x       = (const float*)d_in[0];
  const int*   ei      = (const int*)d_in[1];
  const int*   et      = (const int*)d_in[2];
  const float* rel_w1  = (const float*)d_in[3];
  const float* root_w1 = (const float*)d_in[4];
  const float* b1      = (const float*)d_in[5];
  const float* rel_w2  = (const float*)d_in[6];
  const float* root_w2 = (const float*)d_in[7];
  const float* b2      = (const float*)d_in[8];

  char* ws = (char*)d_ws;
  size_t off = 0;
  auto alloc = [&](size_t bytes) { char* p = ws + off; off = (off + bytes + 255) & ~(size_t)255; return p; };
  unsigned int*   Ypk   = (unsigned int*)alloc((size_t)(EE + NN + 1024) * 64 * 4); // 189.7 MB
  unsigned int*   Xb    = (unsigned int*)alloc((size_t)NN * 64 * 4);         // 25.6 MB
  unsigned int*   h1    = (unsigned int*)alloc((size_t)NN * 64 * 4);         // 25.6 MB
  unsigned short* Wt    = (unsigned short*)alloc((size_t)2 * 9 * DD * DD * 2);
  // ---- zero-span (one memset): cntd, cntdr, cntsr, ysrc ----
  int*            cntd  = (int*)alloc((size_t)NN * 4);
  int*            cntdr = (int*)alloc((size_t)K8 * 4);
  int*            cntsr = (int*)alloc((size_t)K8 * 4);
  int*            ysrc  = (int*)alloc((size_t)(EE + 1024) * 4);
  char*           zend  = ws + off;
  // ---- rest ----
  int*            rowptr= (int*)alloc((size_t)(NN + 1) * 4);
  int*            rowfill=(int*)alloc((size_t)NN * 4);
  int*            pidx  = (int*)alloc((size_t)K8 * 4);
  int2*           recs  = (int2*)alloc((size_t)EE * 8);                      // 5.12 MB
  int*            bsum1 = (int*)alloc((size_t)NSB1 * 4);
  int*            bbase1= (int*)alloc((size_t)NSB1 * 4);
  int*            bsum2 = (int*)alloc((size_t)NSB2 * 4);
  int*            bbase2= (int*)alloc((size_t)NSB2 * 4);
  int*            ub    = (int*)alloc(64);
  int*            pb    = (int*)alloc(64);
  int*            Ptot  = (int*)alloc(64);

  hipMemsetAsync(cntd, 0, (size_t)(zend - (char*)cntd), stream);

  xb_prep<<<(NN * 16) / 256, 256, 0, stream>>>(x, Xb);
  w_prep_all<<<(2 * 9 * DD * DD) / 256, 256, 0, stream>>>(rel_w1, root_w1, rel_w2, root_w2, Wt);
  count_all<<<EE / 256, 256, 0, stream>>>(ei, et, cntd, cntdr, cntsr);

  // dst-degree scan -> rowptr/rowfill
  scan_a<<<NSB1, 256, 0, stream>>>((const int4*)cntd, NN / 4, 0, bsum1);
  scan_b<<<1, 64, 0, stream>>>(bsum1, NSB1, bbase1, nullptr);
  scan_c<<<NSB1, 256, 0, stream>>>(cntd, bbase1, NN, 0, rowptr, rowfill, nullptr);

  // (r,src) usage scan -> raw grank + ub; then pb; then remap + ysrc fill
  scan_a<<<NSB2, 256, 0, stream>>>((const int4*)cntsr, K8 / 4, 1, bsum2);
  scan_b<<<1, 64, 0, stream>>>(bsum2, NSB2, bbase2, Ptot);
  scan_c<<<NSB2, 256, 0, stream>>>(cntsr, bbase2, K8, 1, pidx, nullptr, ub);
  pb_kernel<<<1, 64, 0, stream>>>(ub, Ptot, pb);
  fix_kernel<<<K8 / 256, 256, 0, stream>>>(pidx, ub, pb, ysrc);

  place2<<<EE / 256, 256, 0, stream>>>(ei, et, cntdr, pidx, rowfill, recs);

  const int AB = (NN * 8) / 256;   // 3125

  gemm_y<<<GBMAX, 256, 0, stream>>>(Xb, Wt, ysrc, pb, Ypk);
  aggregate<<<AB, 256, 0, stream>>>(Ypk, rowptr, recs, pb, b1, h1, 1);
  gemm_y<<<GBMAX, 256, 0, stream>>>(h1, Wt + (size_t)9 * DD * DD, ysrc, pb, Ypk);
  aggregate<<<AB, 256, 0, stream>>>(Ypk, rowptr, recs, pb, b2, d_out, 0);
}